// Round 1
// baseline (461.651 us; speedup 1.0000x reference)
//
#include <hip/hip_runtime.h>
#include <hip/hip_bf16.h>

// Problem constants (from reference): B=8, C=192, H=W=128, NH=6, HD=32, N=16384
constexpr int B   = 8;
constexpr int Cc  = 192;
constexpr int H   = 128;
constexpr int Wd  = 128;
constexpr int NH  = 6;
constexpr int HW  = H * Wd;       // 16384
constexpr int QKV = 3 * Cc;       // 576

// Workspace layout (bytes):
//   qkv  : [B][576][HW] fp32            = 301,989,888
//   attn : [B][NH][32][32] fp32         =     196,608
//   ssq  : [2][B][Cc] fp32 (q then k)   =      12,288
//   Mt   : [B][Cc][Cc] fp32 (c-major)   =   1,179,648
constexpr size_t OFF_QKV  = 0;
constexpr size_t OFF_ATTN = 301989888ULL;
constexpr size_t OFF_SSQ  = OFF_ATTN + 196608ULL;
constexpr size_t OFF_MT   = OFF_SSQ + 12288ULL;
constexpr int    N_ZERO   = (196608 + 12288) / 4;   // floats to zero (attn+ssq)

__global__ void zero_kernel(float* __restrict__ p, int n) {
    int i = blockIdx.x * 256 + threadIdx.x;
    if (i < n) p[i] = 0.f;
}

// ---------------------------------------------------------------------------
// K1: grouped 3x3 conv, groups=C, out=3C. Output channel o = 3*g + j uses
// input channel g (JAX group-major ordering). Also accumulates sum-of-squares
// per (b, channel) for q (o<192) and k (192<=o<384).
// grid: (8 row-tiles, 192 groups, 8 batch), block 256.
// ---------------------------------------------------------------------------
constexpr int TS = 16;  // rows per tile

__global__ __launch_bounds__(256) void conv_qkv(
    const float* __restrict__ x, const float* __restrict__ w,
    const float* __restrict__ bias, float* __restrict__ qkv,
    float* __restrict__ ssq)
{
    int tile = blockIdx.x;
    int g    = blockIdx.y;
    int b    = blockIdx.z;
    int y0   = tile * TS;

    __shared__ float sm[TS + 2][Wd + 2];
    __shared__ float red[256];

    const float* xp = x + ((size_t)b * Cc + g) * HW;
    // load rows y0-1 .. y0+TS into sm[r][cx+1]; zero out-of-range rows
    for (int i = threadIdx.x; i < (TS + 2) * Wd; i += 256) {
        int r = i / Wd, cx = i % Wd;
        int y = y0 - 1 + r;
        sm[r][cx + 1] = (y >= 0 && y < H) ? xp[y * Wd + cx] : 0.f;
    }
    for (int i = threadIdx.x; i < (TS + 2) * 2; i += 256) {
        int r = i >> 1;
        sm[r][(i & 1) ? (Wd + 1) : 0] = 0.f;
    }
    __syncthreads();

    bool track = (g < 128);   // q or k channels
    float ssq_local[3] = {0.f, 0.f, 0.f};

    for (int j = 0; j < 3; ++j) {
        int o = 3 * g + j;
        const float* wp = w + (size_t)o * 9;
        float w00 = wp[0], w01 = wp[1], w02 = wp[2];
        float w10 = wp[3], w11 = wp[4], w12 = wp[5];
        float w20 = wp[6], w21 = wp[7], w22 = wp[8];
        float bb = bias[o];
        float* op = qkv + ((size_t)b * QKV + o) * HW;
        for (int p = threadIdx.x; p < TS * Wd; p += 256) {
            int ry = p / Wd, cx = p % Wd;
            int r = ry + 1;
            float s = bb
                + w00 * sm[r - 1][cx] + w01 * sm[r - 1][cx + 1] + w02 * sm[r - 1][cx + 2]
                + w10 * sm[r    ][cx] + w11 * sm[r    ][cx + 1] + w12 * sm[r    ][cx + 2]
                + w20 * sm[r + 1][cx] + w21 * sm[r + 1][cx + 1] + w22 * sm[r + 1][cx + 2];
            op[(size_t)(y0 + ry) * Wd + cx] = s;
            if (track) ssq_local[j] += s * s;
        }
    }

    if (track) {
        for (int j = 0; j < 3; ++j) {
            red[threadIdx.x] = ssq_local[j];
            __syncthreads();
            for (int st = 128; st > 0; st >>= 1) {
                if (threadIdx.x < st) red[threadIdx.x] += red[threadIdx.x + st];
                __syncthreads();
            }
            if (threadIdx.x == 0) {
                int o = 3 * g + j;
                atomicAdd(&ssq[(o < Cc ? 0 : 1) * B * Cc + b * Cc + (o % Cc)], red[0]);
            }
            __syncthreads();
        }
    }
}

// ---------------------------------------------------------------------------
// K2: attn_raw[b,h] += q[b,h] @ k[b,h]^T over an n-segment.
// grid: (16 segments, NH, B), block 256 = 16x16 threads, 2x2 per thread.
// ---------------------------------------------------------------------------
constexpr int NSEG = 16;
constexpr int SEGN = HW / NSEG;   // 1024
constexpr int CH   = 64;

__global__ __launch_bounds__(256) void qk_gemm(
    const float* __restrict__ qkv, float* __restrict__ attn)
{
    int seg = blockIdx.x, h = blockIdx.y, b = blockIdx.z;
    __shared__ float qs[32][CH + 1];
    __shared__ float ks[32][CH + 1];

    const float* qp = qkv + ((size_t)b * QKV + h * 32) * HW + (size_t)seg * SEGN;
    const float* kp = qkv + ((size_t)b * QKV + Cc + h * 32) * HW + (size_t)seg * SEGN;

    int tx = threadIdx.x % 16, ty = threadIdx.x / 16;
    int c0 = ty * 2, d0 = tx * 2;
    float acc00 = 0.f, acc01 = 0.f, acc10 = 0.f, acc11 = 0.f;

    for (int n0 = 0; n0 < SEGN; n0 += CH) {
        for (int i = threadIdx.x; i < 32 * (CH / 4); i += 256) {
            int c = i / (CH / 4), jj = (i % (CH / 4)) * 4;
            float4 v4 = *(const float4*)(qp + (size_t)c * HW + n0 + jj);
            qs[c][jj] = v4.x; qs[c][jj + 1] = v4.y; qs[c][jj + 2] = v4.z; qs[c][jj + 3] = v4.w;
            float4 k4 = *(const float4*)(kp + (size_t)c * HW + n0 + jj);
            ks[c][jj] = k4.x; ks[c][jj + 1] = k4.y; ks[c][jj + 2] = k4.z; ks[c][jj + 3] = k4.w;
        }
        __syncthreads();
        for (int j = 0; j < CH; ++j) {
            float a0 = qs[c0][j], a1 = qs[c0 + 1][j];
            float b0 = ks[d0][j], b1 = ks[d0 + 1][j];
            acc00 += a0 * b0; acc01 += a0 * b1;
            acc10 += a1 * b0; acc11 += a1 * b1;
        }
        __syncthreads();
    }
    float* ap = attn + ((size_t)(b * NH + h) * 32) * 32;
    atomicAdd(&ap[c0 * 32 + d0],           acc00);
    atomicAdd(&ap[c0 * 32 + d0 + 1],       acc01);
    atomicAdd(&ap[(c0 + 1) * 32 + d0],     acc10);
    atomicAdd(&ap[(c0 + 1) * 32 + d0 + 1], acc11);
}

// ---------------------------------------------------------------------------
// K2b: scale by 1/(||q_c|| ||k_d||) * temperature[h], softmax over d, in place.
// grid: 48 (b*NH), block 64 (32 active rows).
// ---------------------------------------------------------------------------
__global__ void softmax_attn(float* __restrict__ attn,
                             const float* __restrict__ ssq,
                             const float* __restrict__ temp)
{
    int h = blockIdx.x % NH, b = blockIdx.x / NH;
    __shared__ float nk[32];
    if (threadIdx.x < 32)
        nk[threadIdx.x] = fmaxf(sqrtf(ssq[B * Cc + b * Cc + h * 32 + threadIdx.x]), 1e-12f);
    __syncthreads();
    int c = threadIdx.x;
    if (c >= 32) return;
    float nq = fmaxf(sqrtf(ssq[b * Cc + h * 32 + c]), 1e-12f);
    float t = temp[h];
    float* ap = attn + ((size_t)(b * NH + h) * 32 + c) * 32;
    float row[32];
    float mx = -1e30f;
    for (int d = 0; d < 32; ++d) {
        float v = ap[d] / (nq * nk[d]) * t;
        row[d] = v;
        mx = fmaxf(mx, v);
    }
    float sum = 0.f;
    for (int d = 0; d < 32; ++d) { row[d] = expf(row[d] - mx); sum += row[d]; }
    float inv = 1.f / sum;
    for (int d = 0; d < 32; ++d) ap[d] = row[d] * inv;
}

// ---------------------------------------------------------------------------
// K3a: fold w_out into attn:  Mt[b][c=h*32+d][o] = sum_{c'} w_out[o][h*32+c'] * attn[b][h][c'][d]
// grid: (NH, B), block 256.
// ---------------------------------------------------------------------------
__global__ __launch_bounds__(256) void make_m(
    const float* __restrict__ attn, const float* __restrict__ w_out,
    float* __restrict__ Mt)
{
    int h = blockIdx.x, b = blockIdx.y;
    __shared__ float as[32][33];
    for (int i = threadIdx.x; i < 1024; i += 256)
        as[i / 32][i % 32] = attn[(size_t)((b * NH + h) * 32 + i / 32) * 32 + i % 32];
    __syncthreads();
    for (int i = threadIdx.x; i < Cc * 32; i += 256) {
        int o = i / 32, d = i % 32;
        const float* wp = w_out + (size_t)o * Cc + h * 32;
        float s = 0.f;
        for (int cp = 0; cp < 32; ++cp) s += wp[cp] * as[cp][d];
        Mt[((size_t)b * Cc + h * 32 + d) * Cc + o] = s;
    }
}

// ---------------------------------------------------------------------------
// K3b: out[b][o][n] = sum_c Mt[b][c][o] * v[b][c][n] + b_out[o]
// block tile: 64 o x 256 n, thread 8x8. grid: (64 n-blocks, 3 o-blocks, B).
// ---------------------------------------------------------------------------
__global__ __launch_bounds__(256) void out_gemm(
    const float* __restrict__ Mt, const float* __restrict__ qkv,
    const float* __restrict__ b_out, float* __restrict__ out)
{
    int n0 = blockIdx.x * 256;
    int o0 = blockIdx.y * 64;
    int b  = blockIdx.z;

    __shared__ float Ms[16][64];
    __shared__ float vs[16][256];

    int tn = threadIdx.x % 32;
    int to = threadIdx.x / 32;   // 0..7

    const float* vp = qkv + ((size_t)b * QKV + 2 * Cc) * HW + n0;
    const float* mp = Mt + (size_t)b * Cc * Cc + o0;

    float acc[8][8];
    for (int r = 0; r < 8; ++r) {
        float bv = b_out[o0 + to * 8 + r];
        for (int s = 0; s < 8; ++s) acc[r][s] = bv;
    }

    for (int c0 = 0; c0 < Cc; c0 += 16) {
        {
            int cc = threadIdx.x / 16, ol = (threadIdx.x % 16) * 4;
            float4 m4 = *(const float4*)(mp + (size_t)(c0 + cc) * Cc + ol);
            Ms[cc][ol] = m4.x; Ms[cc][ol + 1] = m4.y; Ms[cc][ol + 2] = m4.z; Ms[cc][ol + 3] = m4.w;
        }
        for (int i = threadIdx.x; i < 1024; i += 256) {
            int cc = i / 64, j = (i % 64) * 4;
            float4 v4 = *(const float4*)(vp + (size_t)(c0 + cc) * HW + j);
            vs[cc][j] = v4.x; vs[cc][j + 1] = v4.y; vs[cc][j + 2] = v4.z; vs[cc][j + 3] = v4.w;
        }
        __syncthreads();
        for (int cc = 0; cc < 16; ++cc) {
            float mreg[8], vreg[8];
            for (int r = 0; r < 8; ++r) mreg[r] = Ms[cc][to * 8 + r];
            for (int s = 0; s < 8; ++s) vreg[s] = vs[cc][tn + 32 * s];
            for (int r = 0; r < 8; ++r)
                for (int s = 0; s < 8; ++s)
                    acc[r][s] += mreg[r] * vreg[s];
        }
        __syncthreads();
    }

    float* op = out + (size_t)b * Cc * HW + n0;
    for (int r = 0; r < 8; ++r) {
        size_t orow = (size_t)(o0 + to * 8 + r) * HW;
        for (int s = 0; s < 8; ++s)
            op[orow + tn + 32 * s] = acc[r][s];
    }
}

extern "C" void kernel_launch(void* const* d_in, const int* in_sizes, int n_in,
                              void* d_out, int out_size, void* d_ws, size_t ws_size,
                              hipStream_t stream) {
    const float* x      = (const float*)d_in[0];
    const float* w_qkv  = (const float*)d_in[1];
    const float* b_qkv  = (const float*)d_in[2];
    const float* temp   = (const float*)d_in[3];
    const float* w_out  = (const float*)d_in[4];
    const float* b_out  = (const float*)d_in[5];
    float* out = (float*)d_out;

    char* ws = (char*)d_ws;
    float* qkv  = (float*)(ws + OFF_QKV);
    float* attn = (float*)(ws + OFF_ATTN);
    float* ssq  = (float*)(ws + OFF_SSQ);
    float* Mt   = (float*)(ws + OFF_MT);

    zero_kernel<<<(N_ZERO + 255) / 256, 256, 0, stream>>>(attn, N_ZERO);
    conv_qkv<<<dim3(H / TS, Cc, B), 256, 0, stream>>>(x, w_qkv, b_qkv, qkv, ssq);
    qk_gemm<<<dim3(NSEG, NH, B), 256, 0, stream>>>(qkv, attn);
    softmax_attn<<<B * NH, 64, 0, stream>>>(attn, ssq, temp);
    make_m<<<dim3(NH, B), 256, 0, stream>>>(attn, w_out, Mt);
    out_gemm<<<dim3(HW / 256, Cc / 64, B), 256, 0, stream>>>(Mt, qkv, b_out, out);
}

// Round 2
// 289.202 us; speedup vs baseline: 1.5963x; 1.5963x over previous
//
#include <hip/hip_runtime.h>
#include <hip/hip_bf16.h>

// Problem constants: B=8, C=192, H=W=128, NH=6, HD=32, N=16384
constexpr int B   = 8;
constexpr int Cc  = 192;
constexpr int H   = 128;
constexpr int Wd  = 128;
constexpr int NH  = 6;
constexpr int HW  = H * Wd;       // 16384
constexpr int QKV = 3 * Cc;       // 576

typedef short s16x8 __attribute__((ext_vector_type(8)));
typedef float f32x16 __attribute__((ext_vector_type(16)));

// Workspace layout (bytes):
//   qkv  : [B][576][HW] bf16           = 150,994,944
//   attn : [B][NH][32][32] fp32        =     196,608
//   ssq  : [2][B][Cc] fp32 (q then k)  =      12,288
//   M    : [B][192][192] bf16 ([o][c]) =     589,824
constexpr size_t OFF_QKV  = 0;
constexpr size_t OFF_ATTN = 150994944ULL;
constexpr size_t OFF_SSQ  = OFF_ATTN + 196608ULL;
constexpr size_t OFF_M    = OFF_SSQ + 12288ULL;
constexpr int    N_ZERO   = (196608 + 12288) / 4;   // attn+ssq floats

__device__ inline unsigned short f2bf(float f) {
    __hip_bfloat16 h = __float2bfloat16(f);
    return *(unsigned short*)&h;
}

__global__ void zero_kernel(float* __restrict__ p, int n) {
    int i = blockIdx.x * 256 + threadIdx.x;
    if (i < n) p[i] = 0.f;
}

// ---------------------------------------------------------------------------
// K1: grouped 3x3 conv, groups=C, out=3C bf16. o = 3*g + j uses input ch g.
// Window values shared across 3 output channels and 4 x-positions.
// grid: (8 row-tiles, 192 groups, 8 batch), block 256.
// ---------------------------------------------------------------------------
constexpr int TS = 16;

__global__ __launch_bounds__(256) void conv_qkv(
    const float* __restrict__ x, const float* __restrict__ w,
    const float* __restrict__ bias, unsigned short* __restrict__ qkv,
    float* __restrict__ ssq)
{
    int tile = blockIdx.x;
    int g    = blockIdx.y;
    int b    = blockIdx.z;
    int y0   = tile * TS;

    __shared__ float sm[TS + 2][132];   // col c holds x at (c-1); stride 132 for banks
    __shared__ float red[256];

    const float* xp = x + ((size_t)b * Cc + g) * HW;
    // vectorized interior load: 18 rows x 32 float4
    for (int i = threadIdx.x; i < (TS + 2) * 32; i += 256) {
        int r = i >> 5, c4 = (i & 31) * 4;
        int y = y0 - 1 + r;
        if (y >= 0 && y < H) {
            float4 v4 = *(const float4*)(xp + (size_t)y * Wd + c4);
            sm[r][c4 + 1] = v4.x; sm[r][c4 + 2] = v4.y;
            sm[r][c4 + 3] = v4.z; sm[r][c4 + 4] = v4.w;
        } else {
            sm[r][c4 + 1] = 0.f; sm[r][c4 + 2] = 0.f;
            sm[r][c4 + 3] = 0.f; sm[r][c4 + 4] = 0.f;
        }
    }
    for (int i = threadIdx.x; i < (TS + 2) * 2; i += 256) {
        int r = i >> 1;
        sm[r][(i & 1) ? 129 : 0] = 0.f;
    }
    __syncthreads();

    float wreg[3][9], breg[3];
    for (int j = 0; j < 3; ++j) {
        const float* wp = w + (size_t)(3 * g + j) * 9;
        for (int t = 0; t < 9; ++t) wreg[j][t] = wp[t];
        breg[j] = bias[3 * g + j];
    }

    bool track = (g < 128);
    float ss[3] = {0.f, 0.f, 0.f};

    int xq = (threadIdx.x & 31) * 4;
    int ys = threadIdx.x >> 5;

    for (int yy = ys; yy < TS; yy += 8) {
        float rv[3][6];
        for (int r = 0; r < 3; ++r) {
            float4 a4 = *(const float4*)&sm[yy + r][xq];
            float2 a2 = *(const float2*)&sm[yy + r][xq + 4];
            rv[r][0] = a4.x; rv[r][1] = a4.y; rv[r][2] = a4.z;
            rv[r][3] = a4.w; rv[r][4] = a2.x; rv[r][5] = a2.y;
        }
        for (int j = 0; j < 3; ++j) {
            unsigned short pk[4];
            for (int xx = 0; xx < 4; ++xx) {
                float s = breg[j]
                    + wreg[j][0] * rv[0][xx] + wreg[j][1] * rv[0][xx + 1] + wreg[j][2] * rv[0][xx + 2]
                    + wreg[j][3] * rv[1][xx] + wreg[j][4] * rv[1][xx + 1] + wreg[j][5] * rv[1][xx + 2]
                    + wreg[j][6] * rv[2][xx] + wreg[j][7] * rv[2][xx + 1] + wreg[j][8] * rv[2][xx + 2];
                if (track) ss[j] += s * s;
                pk[xx] = f2bf(s);
            }
            unsigned short* op = qkv + ((size_t)b * QKV + 3 * g + j) * HW
                                     + (size_t)(y0 + yy) * Wd + xq;
            *(ushort4*)op = make_ushort4(pk[0], pk[1], pk[2], pk[3]);
        }
    }

    if (track) {
        for (int j = 0; j < 3; ++j) {
            red[threadIdx.x] = ss[j];
            __syncthreads();
            for (int st = 128; st > 0; st >>= 1) {
                if (threadIdx.x < st) red[threadIdx.x] += red[threadIdx.x + st];
                __syncthreads();
            }
            if (threadIdx.x == 0) {
                int o = 3 * g + j;
                atomicAdd(&ssq[(o < Cc ? 0 : 1) * B * Cc + b * Cc + (o % Cc)], red[0]);
            }
            __syncthreads();
        }
    }
}

// ---------------------------------------------------------------------------
// K2: attn[b,h] += q @ k^T via MFMA 32x32x16, fragments loaded straight from
// global (A[m=lane&31][k=(lane>>5)*8+j] == 16B row chunk). 4 waves/block on
// the same (b,h) tile with different K segments; LDS-reduce then one global
// atomic set per block. grid: (16, NH, B), block 256.
// ---------------------------------------------------------------------------
constexpr int NSEG = 64;
constexpr int SEGN = HW / NSEG;   // 256

__global__ __launch_bounds__(256) void qk_mfma(
    const unsigned short* __restrict__ qkv, float* __restrict__ attn)
{
    int h = blockIdx.y, b = blockIdx.z;
    int tid = threadIdx.x;
    int wv = tid >> 6, lane = tid & 63;
    int seg = blockIdx.x * 4 + wv;
    int col = lane & 31, half = lane >> 5;

    __shared__ float sacc[1024];
    for (int i = tid; i < 1024; i += 256) sacc[i] = 0.f;
    __syncthreads();

    const unsigned short* qp = qkv + ((size_t)b * QKV + h * 32 + col) * HW
                                   + seg * SEGN + half * 8;
    const unsigned short* kp = qp + (size_t)Cc * HW;

    f32x16 acc0, acc1;
    for (int i = 0; i < 16; ++i) { acc0[i] = 0.f; acc1[i] = 0.f; }

    for (int kk = 0; kk < SEGN; kk += 32) {
        s16x8 a0 = *(const s16x8*)(qp + kk);
        s16x8 b0 = *(const s16x8*)(kp + kk);
        acc0 = __builtin_amdgcn_mfma_f32_32x32x16_bf16(a0, b0, acc0, 0, 0, 0);
        s16x8 a1 = *(const s16x8*)(qp + kk + 16);
        s16x8 b1 = *(const s16x8*)(kp + kk + 16);
        acc1 = __builtin_amdgcn_mfma_f32_32x32x16_bf16(a1, b1, acc1, 0, 0, 0);
    }

    int rb = half * 4;
    for (int r = 0; r < 16; ++r) {
        int row = (r & 3) + 8 * (r >> 2) + rb;
        atomicAdd(&sacc[row * 32 + col], acc0[r] + acc1[r]);
    }
    __syncthreads();
    float* ap = attn + (size_t)(b * NH + h) * 1024;
    for (int i = tid; i < 1024; i += 256) atomicAdd(&ap[i], sacc[i]);
}

// ---------------------------------------------------------------------------
// K2b: scale by 1/(||q_c|| ||k_d||) * temperature[h], softmax over d.
// ---------------------------------------------------------------------------
__global__ void softmax_attn(float* __restrict__ attn,
                             const float* __restrict__ ssq,
                             const float* __restrict__ temp)
{
    int h = blockIdx.x % NH, b = blockIdx.x / NH;
    __shared__ float nk[32];
    if (threadIdx.x < 32)
        nk[threadIdx.x] = fmaxf(sqrtf(ssq[B * Cc + b * Cc + h * 32 + threadIdx.x]), 1e-12f);
    __syncthreads();
    int c = threadIdx.x;
    if (c >= 32) return;
    float nq = fmaxf(sqrtf(ssq[b * Cc + h * 32 + c]), 1e-12f);
    float t = temp[h];
    float* ap = attn + ((size_t)(b * NH + h) * 32 + c) * 32;
    float row[32];
    float mx = -1e30f;
    for (int d = 0; d < 32; ++d) {
        float v = ap[d] / (nq * nk[d]) * t;
        row[d] = v;
        mx = fmaxf(mx, v);
    }
    float sum = 0.f;
    for (int d = 0; d < 32; ++d) { row[d] = expf(row[d] - mx); sum += row[d]; }
    float inv = 1.f / sum;
    for (int d = 0; d < 32; ++d) ap[d] = row[d] * inv;
}

// ---------------------------------------------------------------------------
// K3a: M[b][o][c=h*32+d] = sum_{c'} w_out[o][h*32+c'] * attn[b][h][c'][d], bf16.
// ---------------------------------------------------------------------------
__global__ __launch_bounds__(256) void make_m(
    const float* __restrict__ attn, const float* __restrict__ w_out,
    unsigned short* __restrict__ M)
{
    int h = blockIdx.x, b = blockIdx.y;
    __shared__ float as[32][33];
    for (int i = threadIdx.x; i < 1024; i += 256)
        as[i / 32][i % 32] = attn[(size_t)((b * NH + h) * 32 + i / 32) * 32 + i % 32];
    __syncthreads();
    for (int i = threadIdx.x; i < Cc * 32; i += 256) {
        int o = i / 32, d = i % 32;
        const float* wp = w_out + (size_t)o * Cc + h * 32;
        float s = 0.f;
        for (int cp = 0; cp < 32; ++cp) s += wp[cp] * as[cp][d];
        M[((size_t)b * Cc + o) * Cc + h * 32 + d] = f2bf(s);
    }
}

// ---------------------------------------------------------------------------
// K3b: out[b][o][n] = sum_c M[o][c] * v[c][n] + b_out[o] via MFMA 32x32x16.
// Block tile: o=192 (all) x n=128; 4 waves = 2(m) x 2(n); wave: 96o x 64n.
// v transposed through LDS (vsT[n][c], stride 24 shorts). grid: (128, 8).
// ---------------------------------------------------------------------------
constexpr int BN = 128;

__global__ __launch_bounds__(256) void out_gemm(
    const unsigned short* __restrict__ M, const unsigned short* __restrict__ qkv,
    const float* __restrict__ b_out, float* __restrict__ out)
{
    int n0 = blockIdx.x * BN;
    int b  = blockIdx.y;

    const unsigned short* vp = qkv + ((size_t)b * QKV + 2 * Cc) * HW;
    const unsigned short* mp = M + (size_t)b * Cc * Cc;

    __shared__ unsigned short vsT[BN][24];   // 16 used, stride 24 (48B, b128-aligned)

    int tid  = threadIdx.x;
    int lane = tid & 63, wv = tid >> 6;
    int wm = wv & 1, wn = wv >> 1;
    int col = lane & 31, half = lane >> 5;

    f32x16 acc[6];
    for (int t = 0; t < 6; ++t)
        for (int i = 0; i < 16; ++i) acc[t][i] = 0.f;

    int p  = tid >> 5;   // 0..7 channel-pair
    int nq = tid & 31;   // 0..31 n-quad

    for (int k0 = 0; k0 < Cc; k0 += 16) {
        const unsigned short* s0 = vp + (size_t)(k0 + 2 * p) * HW + n0 + 4 * nq;
        ushort4 va = *(const ushort4*)s0;
        ushort4 vb = *(const ushort4*)(s0 + HW);
        *(unsigned int*)&vsT[4 * nq + 0][2 * p] = (unsigned int)va.x | ((unsigned int)vb.x << 16);
        *(unsigned int*)&vsT[4 * nq + 1][2 * p] = (unsigned int)va.y | ((unsigned int)vb.y << 16);
        *(unsigned int*)&vsT[4 * nq + 2][2 * p] = (unsigned int)va.z | ((unsigned int)vb.z << 16);
        *(unsigned int*)&vsT[4 * nq + 3][2 * p] = (unsigned int)va.w | ((unsigned int)vb.w << 16);
        __syncthreads();

        s16x8 af[3], bf[2];
        for (int mt = 0; mt < 3; ++mt) {
            int o = wm * 96 + mt * 32 + col;
            af[mt] = *(const s16x8*)(mp + (size_t)o * Cc + k0 + half * 8);
        }
        for (int nt = 0; nt < 2; ++nt) {
            int nn = wn * 64 + nt * 32 + col;
            bf[nt] = *(const s16x8*)&vsT[nn][half * 8];
        }
        for (int mt = 0; mt < 3; ++mt)
            for (int nt = 0; nt < 2; ++nt)
                acc[mt * 2 + nt] = __builtin_amdgcn_mfma_f32_32x32x16_bf16(
                    af[mt], bf[nt], acc[mt * 2 + nt], 0, 0, 0);
        __syncthreads();
    }

    for (int mt = 0; mt < 3; ++mt)
        for (int nt = 0; nt < 2; ++nt) {
            f32x16 c = acc[mt * 2 + nt];
            int n = n0 + wn * 64 + nt * 32 + col;
            for (int r = 0; r < 16; ++r) {
                int row = (r & 3) + 8 * (r >> 2) + 4 * half;
                int o = wm * 96 + mt * 32 + row;
                out[((size_t)b * Cc + o) * HW + n] = c[r] + b_out[o];
            }
        }
}

extern "C" void kernel_launch(void* const* d_in, const int* in_sizes, int n_in,
                              void* d_out, int out_size, void* d_ws, size_t ws_size,
                              hipStream_t stream) {
    const float* x      = (const float*)d_in[0];
    const float* w_qkv  = (const float*)d_in[1];
    const float* b_qkv  = (const float*)d_in[2];
    const float* temp   = (const float*)d_in[3];
    const float* w_out  = (const float*)d_in[4];
    const float* b_out  = (const float*)d_in[5];
    float* out = (float*)d_out;

    char* ws = (char*)d_ws;
    unsigned short* qkv = (unsigned short*)(ws + OFF_QKV);
    float* attn         = (float*)(ws + OFF_ATTN);
    float* ssq          = (float*)(ws + OFF_SSQ);
    unsigned short* M   = (unsigned short*)(ws + OFF_M);

    zero_kernel<<<(N_ZERO + 255) / 256, 256, 0, stream>>>(attn, N_ZERO);
    conv_qkv<<<dim3(H / TS, Cc, B), 256, 0, stream>>>(x, w_qkv, b_qkv, qkv, ssq);
    qk_mfma<<<dim3(NSEG / 4, NH, B), 256, 0, stream>>>(qkv, attn);
    softmax_attn<<<B * NH, 64, 0, stream>>>(attn, ssq, temp);
    make_m<<<dim3(NH, B), 256, 0, stream>>>(attn, w_out, M);
    out_gemm<<<dim3(HW / BN, B), 256, 0, stream>>>(M, qkv, b_out, out);
}